// Round 14
// baseline (43.252 us; speedup 1.0000x reference)
//
#include <hip/hip_runtime.h>

// DivEncLayer via MFMA — fully WAVE-INDEPENDENT: each wave owns all 4 q's of
// its q-tile for its own 32-row group. 4 independent MFMA+epilogue chains per
// iteration, wave-private LDS panel, ZERO __syncthreads anywhere.
// Per (b,q): h = elu(x[b,q*8:+8]@W1[q] + b1[q]); LN(h); out = h@W2[q]+b2[q].
// B=16384, Q=128, S=8, U=32.
//
// r12/r13 post-mortem: raw-asm permlane32_swap has unknown semantics (two
// identical failures) -> reverted to proven __shfl_xor combine. r5-r11 review:
// all ~30us variants shared barrier-locked waves + 1 dependent chain per wave;
// this round decorrelates waves completely and gives each wave 4 chains.
//
// v_mfma_f32_32x32x16_bf16 mapping (validated r2-r11, all passing rounds):
//   A: lane l, reg j -> A[l&31][j + 8*(l>>5)]
//   B: lane l, reg j -> B[j + 8*(l>>5)][l&31]
//   D: lane l, reg r -> row u=(r&3)+8*(r>>2)+4*(l>>5), col b=l&31
// Packed A-frag: lanes<32 = bf16(W1^T) (k<8), lanes>=32 = bf16(W1-hi) (k>=8).
// B-frag: panel row (l&31), cols qq*8..+7 — halves read the same 16B (dup),
// so D = (whi+wlo)*xhi + b1 (C-in fp32). LN+Dense2 folded:
//   out = rsqrt(var+eps)*(dot(e,g2) - mu*G) + C.
//
// Staging: wave's panel = its 32 rows x 32 cols (x[:, qt*32..+31], 4KB fp32).
// 8 lanes/row fully-coalesced float4 loads (4 instr/wave/iter), cvt to bf16,
// pitch 40 shorts (80B: 16B-aligned b128 reads, 4-way conflict max = free-ish).
// Same-wave DS ordering: reads of iter N precede writes of iter N+1 in program
// order -> no barrier needed, panel is single-buffered.
// Output: after shfl-combine all lanes hold res[qq]; lanes<32 store one float4
// per row (write-exact ~8.5MB). Grid (32,32): 4 iters x 128 rows per block.

typedef __attribute__((ext_vector_type(8))) short short8;    // 8 bf16
typedef __attribute__((ext_vector_type(16))) float f32x16;

#define PITCH 40   // shorts per panel row (80 B)

__device__ __forceinline__ short fbits(__bf16 b) { return __builtin_bit_cast(short, b); }

__device__ __forceinline__ float elu1(float v) {
    return v > 0.f ? v : __expf(v) - 1.f;
}

__device__ __forceinline__ short4 cvt4(float4 v) {
    short4 r;
    r.x = fbits((__bf16)v.x); r.y = fbits((__bf16)v.y);
    r.z = fbits((__bf16)v.z); r.w = fbits((__bf16)v.w);
    return r;
}

__global__ __launch_bounds__(256, 2) void divenc_mfma(
    const float* __restrict__ x,      // (16384, 1024)
    const float* __restrict__ W1,     // (128, 8, 32)
    const float* __restrict__ b1,     // (128, 32)
    const float* __restrict__ gamma,  // (128, 32)
    const float* __restrict__ beta,   // (128, 32)
    const float* __restrict__ W2,     // (128, 32)
    const float* __restrict__ b2,     // (128,)
    float* __restrict__ out)          // (16384, 128)
{
    __shared__ short xs[4][32 * PITCH];   // wave-private panels (2560 B each)

    const int tid  = threadIdx.x;
    const int w    = tid >> 6;
    const int ln   = tid & 63;
    const int u    = ln & 31;
    const int half = ln >> 5;
    const int qt   = blockIdx.y;          // 0..31
    const int bx   = blockIdx.x;          // 0..31
    const int band = bx * 512;
    short* panel   = &xs[w][0];

    // staging roles: 8 lanes per row, 4 rows per lane (srow, +8, +16, +24)
    const int srow = ln >> 3;             // 0..7
    const int schk = ln & 7;              // 16B chunk within the 128B row
    const float* xg = x + qt * 32 + schk * 4;

    // ---- A-frags (4 q): lanes<32 = whi (k<8), lanes>=32 = wlo (k>=8) ----
    short8 wfrag[4];
    #pragma unroll
    for (int qq = 0; qq < 4; ++qq) {
        const int q = qt * 4 + qq;
        #pragma unroll
        for (int j = 0; j < 8; ++j) {
            float f  = W1[q * 256 + j * 32 + u];
            __bf16 h = (__bf16)f;
            wfrag[qq][j] = half ? fbits((__bf16)(f - (float)h)) : fbits(h);
        }
    }

    // ---- params per q: biasr (MFMA C-in) + g2r regs; G, C scalars ----
    f32x16 biasr[4], g2r[4];
    float G[4], C[4];
    #pragma unroll
    for (int qq = 0; qq < 4; ++qq) {
        const int q = qt * 4 + qq;
        float gs = 0.f, cs = 0.f;
        #pragma unroll
        for (int c = 0; c < 4; ++c) {
            const int ub = q * 32 + 4 * half + 8 * c;
            float4 b1v = *(const float4*)&b1[ub];
            float4 gav = *(const float4*)&gamma[ub];
            float4 w2v = *(const float4*)&W2[ub];
            float4 bev = *(const float4*)&beta[ub];
            #pragma unroll
            for (int j = 0; j < 4; ++j) {
                float g2 = ((const float*)&gav)[j] * ((const float*)&w2v)[j];
                biasr[qq][4 * c + j] = ((const float*)&b1v)[j];
                g2r[qq][4 * c + j]   = g2;
                gs += g2;
                cs += ((const float*)&bev)[j] * ((const float*)&w2v)[j];
            }
        }
        gs += __shfl_xor(gs, 32);   // halves hold complementary u-sets
        cs += __shfl_xor(cs, 32);
        G[qq] = gs;
        C[qq] = cs + b2[q];
    }

    // ---- prime panel for iter 0 (fully coalesced, wave-private) ----
    {
        const float* base = xg + (size_t)(band + w * 32 + srow) * 1024;
        float4 a0 = *(const float4*)(base);
        float4 a1 = *(const float4*)(base +  8 * 1024);
        float4 a2 = *(const float4*)(base + 16 * 1024);
        float4 a3 = *(const float4*)(base + 24 * 1024);
        *(short4*)&panel[(srow     ) * PITCH + schk * 4] = cvt4(a0);
        *(short4*)&panel[(srow +  8) * PITCH + schk * 4] = cvt4(a1);
        *(short4*)&panel[(srow + 16) * PITCH + schk * 4] = cvt4(a2);
        *(short4*)&panel[(srow + 24) * PITCH + schk * 4] = cvt4(a3);
    }

    #pragma unroll 1
    for (int it = 0; it < 4; ++it) {
        const int rowbase = band + it * 128 + w * 32;

        // issue next panel's loads early (hidden under this iter's compute)
        float4 n0, n1, n2, n3;
        if (it < 3) {
            const float* nb = xg + (size_t)(rowbase + 128 + srow) * 1024;
            n0 = *(const float4*)(nb);
            n1 = *(const float4*)(nb +  8 * 1024);
            n2 = *(const float4*)(nb + 16 * 1024);
            n3 = *(const float4*)(nb + 24 * 1024);
        }

        // ---- 4 independent MFMA + epilogue chains ----
        float res[4];
        #pragma unroll
        for (int qq = 0; qq < 4; ++qq) {
            // B-frag: row (l&31), cols qq*8..+7; halves dup the same 16B
            short8 xf = *(const short8*)&panel[u * PITCH + qq * 8];
            f32x16 acc = __builtin_amdgcn_mfma_f32_32x32x16_bf16(
                             wfrag[qq], xf, biasr[qq], 0, 0, 0);

            float sum = 0.f, ss = 0.f, dot = 0.f;
            #pragma unroll
            for (int r = 0; r < 16; ++r) {
                float e = elu1(acc[r]);
                sum += e;
                ss  = fmaf(e, e, ss);
                dot = fmaf(e, g2r[qq][r], dot);
            }
            sum += __shfl_xor(sum, 32);    // proven combine (r2-r11)
            ss  += __shfl_xor(ss, 32);
            dot += __shfl_xor(dot, 32);
            float mu  = sum * 0.03125f;
            float var = fmaf(-mu, mu, ss * 0.03125f);
            float inv = rsqrtf(var + 1e-3f);
            res[qq] = fmaf(inv, fmaf(-mu, G[qq], dot), C[qq]);
        }

        // direct store: lane u owns row rowbase+u, cols qt*4..+3 (16B exact)
        if (half == 0) {
            float4 o = {res[0], res[1], res[2], res[3]};
            *(float4*)(out + (size_t)(rowbase + u) * 128 + qt * 4) = o;
        }

        // write next panel AFTER all reads of current (same-wave DS ordering)
        if (it < 3) {
            *(short4*)&panel[(srow     ) * PITCH + schk * 4] = cvt4(n0);
            *(short4*)&panel[(srow +  8) * PITCH + schk * 4] = cvt4(n1);
            *(short4*)&panel[(srow + 16) * PITCH + schk * 4] = cvt4(n2);
            *(short4*)&panel[(srow + 24) * PITCH + schk * 4] = cvt4(n3);
        }
    }
}

extern "C" void kernel_launch(void* const* d_in, const int* in_sizes, int n_in,
                              void* d_out, int out_size, void* d_ws, size_t ws_size,
                              hipStream_t stream) {
    const float* x     = (const float*)d_in[0];
    const float* W1    = (const float*)d_in[1];
    const float* b1    = (const float*)d_in[2];
    const float* gamma = (const float*)d_in[3];
    const float* beta  = (const float*)d_in[4];
    const float* W2    = (const float*)d_in[5];
    const float* b2    = (const float*)d_in[6];
    float* out = (float*)d_out;

    dim3 grid(32, 32);   // (512-row bands, q-tiles of 4)
    divenc_mfma<<<grid, 256, 0, stream>>>(x, W1, b1, gamma, beta, W2, b2, out);
}